// Round 19
// baseline (377.638 us; speedup 1.0000x reference)
//
#include <hip/hip_runtime.h>

typedef _Float16 f16;
typedef __attribute__((ext_vector_type(2))) _Float16 f16x2;
typedef __attribute__((ext_vector_type(4))) _Float16 f16x4;
typedef __attribute__((ext_vector_type(8))) _Float16 f16x8;
typedef __attribute__((ext_vector_type(4))) float f32x4;
typedef __attribute__((ext_vector_type(16))) float f32x16;

#define BM 128
#define BN 128
#define BK 32

__device__ __forceinline__ void gl_lds16(const void* g, void* l) {
    __builtin_amdgcn_global_load_lds(
        (const __attribute__((address_space(1))) void*)g,
        (__attribute__((address_space(3))) void*)l, 16, 0, 0);
}

// ---------------------------------------------------------------------------
// Fused: 6x transpose+convert (blocks 0..583) + bottom layer 0 (registers+LDS).
// ---------------------------------------------------------------------------
struct ConvtDesc { const float* src; f16* dst; int K, N, Kpad, tileOff; };
struct ConvtArgs { ConvtDesc d[6]; };

__global__ void convtbot_kernel(ConvtArgs args, const float* __restrict__ xin,
                                const float* __restrict__ bw0,
                                const float* __restrict__ bb0, f16* __restrict__ act0)
{
    int tid = threadIdx.x;
    if (blockIdx.x >= 584) {
        __shared__ float xs[64][13];
        int rbase = (blockIdx.x - 584) * 64;
        int n0 = tid * 2;
        float wr0[13], wr1[13];
        #pragma unroll
        for (int k = 0; k < 13; ++k) {
            wr0[k] = bw0[k * 512 + n0];
            wr1[k] = bw0[k * 512 + n0 + 1];
        }
        float b0v = bb0[n0], b1v = bb0[n0 + 1];
        for (int t = tid; t < 64 * 13; t += 256)
            xs[t / 13][t % 13] = xin[(size_t)rbase * 13 + t];
        __syncthreads();
        #pragma unroll 4
        for (int r = 0; r < 64; ++r) {
            float a0 = b0v, a1 = b1v;
            #pragma unroll
            for (int k = 0; k < 13; ++k) {
                float xv = xs[r][k];
                a0 += xv * wr0[k];
                a1 += xv * wr1[k];
            }
            f16x2 v;
            v[0] = (f16)fmaxf(a0, 0.f);
            v[1] = (f16)fmaxf(a1, 0.f);
            *(f16x2*)(act0 + (size_t)(rbase + r) * 512 + n0) = v;
        }
        return;
    }
    __shared__ float tile[64][65];
    int bid = blockIdx.x;
    int w = 0;
    #pragma unroll
    for (int i = 1; i < 6; ++i) if (bid >= args.d[i].tileOff) w = i;
    const float* __restrict__ src = args.d[w].src;
    f16* __restrict__ dst = args.d[w].dst;
    int K = args.d[w].K, N = args.d[w].N, Kpad = args.d[w].Kpad;
    int local = bid - args.d[w].tileOff;
    int tk = Kpad >> 6;
    int k0 = (local % tk) * 64;
    int n0 = (local / tk) * 64;
    #pragma unroll
    for (int it = 0; it < 16; ++it) {
        int idx = it * 256 + tid;
        int kr = idx >> 6, nc = idx & 63;
        float v = 0.f;
        if (k0 + kr < K) v = src[(size_t)(k0 + kr) * N + n0 + nc];
        tile[kr][nc] = v;
    }
    __syncthreads();
    #pragma unroll
    for (int it = 0; it < 16; ++it) {
        int idx = it * 256 + tid;
        int nr = idx >> 6, kc = idx & 63;
        dst[(size_t)(n0 + nr) * Kpad + k0 + kc] = (f16)tile[kc][nr];
    }
}

// ---------------------------------------------------------------------------
// 128x128 MFMA f16 GEMM, BK=32, double-buffered, counted-vmcnt, LDS-bounce
// epilogue. w4 != nullptr -> fused final-layer partial dot (r18-verified).
// ---------------------------------------------------------------------------
__global__ void gemm_f16(const f16* __restrict__ A, const f16* __restrict__ WT,
                         const float* __restrict__ bias, f16* __restrict__ C,
                         int N, int K,
                         const float* __restrict__ w4, float* __restrict__ partial)
{
    __shared__ __align__(16) f16 sm[16384];
    f16* lsA0 = sm;
    f16* lsB0 = sm + 8192;
    int tid  = threadIdx.x;
    int lane = tid & 63;
    int wave = tid >> 6;
    int brow = blockIdx.y * BM;
    int bcol = blockIdx.x * BN;
    int wr = wave >> 1, wc = wave & 1;

    int rsel = lane & 15;
    int k8   = lane >> 4;

    auto stage = [&](int buf, int kt) {
        int k0 = kt * BK;
        #pragma unroll
        for (int i = 0; i < 2; ++i) {
            int flat = i * 256 + tid;
            int row  = flat >> 2;
            int slot = flat & 3;
            int sg   = slot ^ ((row >> 1) & 3);
            gl_lds16(A  + (size_t)(brow + row) * K + k0 + sg * 8, lsA0 + buf * 4096 + flat * 8);
            gl_lds16(WT + (size_t)(bcol + row) * K + k0 + sg * 8, lsB0 + buf * 4096 + flat * 8);
        }
    };

    int nK = K / BK;
    f32x4 acc[4][4] = {};
    stage(0, 0);
    for (int kt = 0; kt < nK; ++kt) {
        int cur = kt & 1;
        if (kt + 1 < nK) {
            stage(cur ^ 1, kt + 1);
            asm volatile("s_waitcnt vmcnt(4)" ::: "memory");
        } else {
            asm volatile("s_waitcnt vmcnt(0)" ::: "memory");
        }
        __builtin_amdgcn_s_barrier();

        __builtin_amdgcn_s_setprio(1);
        f16x8 aF[4], bF[4];
        #pragma unroll
        for (int m = 0; m < 4; ++m) {
            int ra = wr * 64 + m * 16 + rsel;
            int sa = k8 ^ ((ra >> 1) & 3);
            aF[m] = *(const f16x8*)(lsA0 + cur * 4096 + ra * 32 + sa * 8);
        }
        #pragma unroll
        for (int n = 0; n < 4; ++n) {
            int rb = wc * 64 + n * 16 + rsel;
            int sb = k8 ^ ((rb >> 1) & 3);
            bF[n] = *(const f16x8*)(lsB0 + cur * 4096 + rb * 32 + sb * 8);
        }
        #pragma unroll
        for (int m = 0; m < 4; ++m)
            #pragma unroll
            for (int n = 0; n < 4; ++n)
                acc[m][n] = __builtin_amdgcn_mfma_f32_16x16x32_f16(aF[m], bF[n], acc[m][n], 0, 0, 0);
        __builtin_amdgcn_s_setprio(0);
        asm volatile("s_waitcnt lgkmcnt(0)" ::: "memory");
        __builtin_amdgcn_s_barrier();
    }

    #pragma unroll
    for (int n = 0; n < 4; ++n) {
        int col = wc * 64 + n * 16 + rsel;
        float bv = bias[bcol + col];
        int ch = (col >> 3) ^ (k8 << 2);
        #pragma unroll
        for (int m = 0; m < 4; ++m) {
            int row = wr * 64 + m * 16 + k8 * 4;
            #pragma unroll
            for (int r = 0; r < 4; ++r)
                sm[(row + r) * 128 + ch * 8 + (col & 7)] = (f16)fmaxf(acc[m][n][r] + bv, 0.f);
        }
    }
    __syncthreads();
    if (w4 == nullptr) {
        int ch = tid & 15, r0 = tid >> 4;
        #pragma unroll
        for (int p = 0; p < 8; ++p) {
            int row = r0 + p * 16;
            int sch = ch ^ (((row >> 2) & 3) << 2);
            f16x8 v = *(const f16x8*)(sm + row * 128 + sch * 8);
            *(f16x8*)(C + (size_t)(brow + row) * N + bcol + ch * 8) = v;
        }
    } else {
        int r = tid >> 1, h = tid & 1;
        int s4 = ((r >> 2) & 3) << 2;
        float a2 = 0.f;
        #pragma unroll
        for (int i = 0; i < 8; ++i) {
            int cc = h * 8 + i;
            f16x8 cv = *(const f16x8*)(sm + r * 128 + (cc ^ s4) * 8);
            #pragma unroll
            for (int e = 0; e < 8; ++e)
                a2 += (float)cv[e] * w4[bcol + cc * 8 + e];
        }
        a2 += __shfl_xor(a2, 1, 64);
        if (h == 0) partial[(size_t)(brow + r) * 2 + blockIdx.x] = a2;
    }
}

// ---------------------------------------------------------------------------
// finish: out[b] = relu(partial[b][0] + partial[b][1] + bias)
// ---------------------------------------------------------------------------
__global__ void finish_kernel(const float* __restrict__ partial,
                              const float* __restrict__ b4, float* __restrict__ out)
{
    int b = blockIdx.x * 256 + threadIdx.x;
    out[b] = fmaxf(partial[(size_t)b * 2] + partial[(size_t)b * 2 + 1] + b4[0], 0.f);
}

// ---------------------------------------------------------------------------
// 256x256 MFMA f16 GEMM, BK=64, 8 waves — r19: 32x32x16 fragments, 2-phase
// K-tile (phase=M-half). Per phase: 16 MFMA of 32x32x16 (2x FLOP/instr vs
// 16x16x32), 4 barriers/K-tile. bF held in regs across both phases (24
// ds_read_b128 per K-tile per wave, unchanged). vmcnt protocol identical to
// r13-verified: prologue VM(2); phase-A VM(4) lands A1; phase-B VM(2) lands
// next-tile A0,B0,B1; tail VM(0); LGKM0 before each K-tile's final barrier.
// A-frag layout (inferred): row=lane&31, k-octet=lane>>5. C/D: col=lane&31,
// row=(r&3)+8*(r>>2)+4*(lane>>5). Epilogue swizzle = pure f(row,col).
// ---------------------------------------------------------------------------
#define VM(n) asm volatile("s_waitcnt vmcnt(" #n ")" ::: "memory")
#define LGKM0 asm volatile("s_waitcnt lgkmcnt(0)" ::: "memory")

__global__ __launch_bounds__(512, 2) void gemm256_8ph(
    const f16* __restrict__ A, const f16* __restrict__ WT,
    const float* __restrict__ bias, f16* __restrict__ C, int N, int K)
{
    __shared__ __align__(16) f16 ls[2 * 4 * 128 * 64];   // 128 KiB
    int tid  = threadIdx.x;
    int lane = tid & 63;
    int wid  = tid >> 6;
    int wmq = wid >> 2, wnq = wid & 3;
    int l31 = lane & 31, h = lane >> 5;

    int nbx = gridDim.x;
    int flat = blockIdx.y * nbx + blockIdx.x;
    int nchunk = (nbx * gridDim.y) >> 3;
    int nf = (flat & 7) * nchunk + (flat >> 3);
    int bx = nf % nbx, by = nf / nbx;
    int brow = by * 256, bcol = bx * 256;

    const size_t szK = (size_t)K;

    // half regions: 0=A-half0, 1=B-half0, 2=A-half1, 3=B-half1 (8192 f16 each)
    auto stage_half = [&](int dbuf, int hreg, int kt) {
        const f16* mat = (hreg & 1) ? WT : A;
        int base = (hreg & 1) ? bcol : brow;
        const f16* g = mat + (size_t)(base + (hreg >> 1) * 128) * szK + kt * 64;
        f16* d = ls + dbuf * 32768 + hreg * 8192;
        #pragma unroll
        for (int i = 0; i < 2; ++i) {
            int fl  = i * 512 + tid;
            int row = fl >> 3, sl = fl & 7;
            int sg  = sl ^ (row & 7);
            gl_lds16(g + (size_t)row * szK + sg * 8, d + fl * 8);
        }
    };

    int nK = K / 64;
    f32x16 acc[2][2][2] = {};   // [mh][m][n]
    f16x8 bF[2][4];             // [n][kk], live across both phases
    int bregion = 1 + ((wnq >> 1) << 1);          // B0 for wnq 0,1; B1 for 2,3
    int broff0 = (wnq & 1) * 64;                  // row-in-region base

    stage_half(0, 0, 0); stage_half(0, 1, 0);
    stage_half(0, 3, 0); stage_half(0, 2, 0);
    VM(2);
    __builtin_amdgcn_s_barrier();

    for (int kt = 0; kt < nK; ++kt) {
        int cb = kt & 1, nb = cb ^ 1;
        bool nl = (kt + 1 < nK);
        f16x8 aF[2][4];
        // ---- phase A (mh=0): A-half0 rows wmq*64+m*32; read ALL bF
        {
            const f16* pA = ls + cb * 32768 + 0 * 8192;
            #pragma unroll
            for (int m = 0; m < 2; ++m) {
                int roff = wmq * 64 + m * 32 + l31;
                #pragma unroll
                for (int kk = 0; kk < 4; ++kk) {
                    int s = (kk * 2 + h) ^ (roff & 7);
                    aF[m][kk] = *(const f16x8*)(pA + roff * 64 + s * 8);
                }
            }
            const f16* pB = ls + cb * 32768 + bregion * 8192;
            #pragma unroll
            for (int n = 0; n < 2; ++n) {
                int roff = broff0 + n * 32 + l31;
                #pragma unroll
                for (int kk = 0; kk < 4; ++kk) {
                    int s = (kk * 2 + h) ^ (roff & 7);
                    bF[n][kk] = *(const f16x8*)(pB + roff * 64 + s * 8);
                }
            }
        }
        if (nl) { stage_half(nb, 0, kt + 1); stage_half(nb, 1, kt + 1); VM(4); }
        else    { VM(0); }
        __builtin_amdgcn_s_barrier();
        __builtin_amdgcn_s_setprio(1);
        #pragma unroll
        for (int kk = 0; kk < 4; ++kk)
            #pragma unroll
            for (int m = 0; m < 2; ++m)
                #pragma unroll
                for (int n = 0; n < 2; ++n)
                    acc[0][m][n] = __builtin_amdgcn_mfma_f32_32x32x16_f16(
                        aF[m][kk], bF[n][kk], acc[0][m][n], 0, 0, 0);
        __builtin_amdgcn_s_setprio(0);
        __builtin_amdgcn_s_barrier();
        // ---- phase B (mh=1): A-half1
        {
            const f16* pA = ls + cb * 32768 + 2 * 8192;
            #pragma unroll
            for (int m = 0; m < 2; ++m) {
                int roff = wmq * 64 + m * 32 + l31;
                #pragma unroll
                for (int kk = 0; kk < 4; ++kk) {
                    int s = (kk * 2 + h) ^ (roff & 7);
                    aF[m][kk] = *(const f16x8*)(pA + roff * 64 + s * 8);
                }
            }
        }
        if (nl) { stage_half(nb, 3, kt + 1); stage_half(nb, 2, kt + 1); VM(2); }
        __builtin_amdgcn_s_barrier();
        __builtin_amdgcn_s_setprio(1);
        #pragma unroll
        for (int kk = 0; kk < 4; ++kk)
            #pragma unroll
            for (int m = 0; m < 2; ++m)
                #pragma unroll
                for (int n = 0; n < 2; ++n)
                    acc[1][m][n] = __builtin_amdgcn_mfma_f32_32x32x16_f16(
                        aF[m][kk], bF[n][kk], acc[1][m][n], 0, 0, 0);
        __builtin_amdgcn_s_setprio(0);
        LGKM0;
        __builtin_amdgcn_s_barrier();
    }

    // epilogue: acc -> ls as 256x256 f16 C-tile (swizzle = pure f(row,col))
    #pragma unroll
    for (int mh = 0; mh < 2; ++mh)
        #pragma unroll
        for (int m = 0; m < 2; ++m)
            #pragma unroll
            for (int n = 0; n < 2; ++n) {
                int col = wnq * 64 + n * 32 + l31;
                float bv = bias[bcol + col];
                #pragma unroll
                for (int r = 0; r < 16; ++r) {
                    int row = mh * 128 + wmq * 64 + m * 32 + (r & 3) + 8 * (r >> 2) + 4 * h;
                    int ch = (col >> 3) ^ (((row >> 2) & 3) << 2);
                    ls[row * 256 + ch * 8 + (col & 7)] = (f16)fmaxf(acc[mh][m][n][r] + bv, 0.f);
                }
            }
    __syncthreads();
    {
        int ch = tid & 31, r0 = tid >> 5;
        #pragma unroll
        for (int p = 0; p < 16; ++p) {
            int row = r0 + p * 16;
            int sch = ch ^ (((row >> 2) & 3) << 2);
            f16x8 v = *(const f16x8*)(ls + row * 256 + sch * 8);
            *(f16x8*)(C + (size_t)(brow + row) * N + bcol + ch * 8) = v;
        }
    }
}

// ---------------------------------------------------------------------------
// MFMA interaction: 4 samples/block, one wave per sample. 32 KiB LDS
// (xs overlaid on F rows 27..30) -> 5 blocks/CU.
// ---------------------------------------------------------------------------
__global__ void interact_mfma(const f16* __restrict__ botout,
                              const float* __restrict__ emb,
                              const int* __restrict__ sparse,
                              f16* __restrict__ x, int V)
{
    __shared__ __align__(16) f16 F[4][32][128];
    int tid  = threadIdx.x;
    int lane = tid & 63, wave = tid >> 6;
    int b0 = blockIdx.x * 4;
    f16* xs_w = &F[wave][27][0];

    for (int t = tid; t < 4 * 27 * 16; t += 256) {
        int s   = t / (27 * 16);
        int rem = t - s * (27 * 16);
        int r   = rem >> 4;
        int c   = rem & 15;
        int b   = b0 + s;
        f16x8 v;
        if (r == 0) {
            v = *(const f16x8*)(botout + (size_t)b * 128 + c * 8);
        } else {
            const f32x4* src = (const f32x4*)(emb + ((size_t)(r - 1) * V + sparse[b * 26 + (r - 1)]) * 128 + c * 8);
            f32x4 u0 = src[0], u1 = src[1];
            #pragma unroll
            for (int e = 0; e < 4; ++e) { v[e] = (f16)u0[e]; v[4 + e] = (f16)u1[e]; }
        }
        *(f16x8*)(&F[s][r][(c ^ (r & 15)) * 8]) = v;
    }
    if (tid < 4 * 33) {
        int s = tid / 33;
        (&F[s][27][0])[479 + tid % 33] = (f16)0;
    }
    __syncthreads();

    f32x4 a00 = {}, a10 = {}, a11 = {};
    int rl = lane & 15, ch = lane >> 4;
    #pragma unroll
    for (int ks = 0; ks < 4; ++ks) {
        int c = ks * 4 + ch;
        f16x8 f0 = *(const f16x8*)(&F[wave][rl]     [(c ^ rl) * 8]);
        f16x8 f1 = *(const f16x8*)(&F[wave][16 + rl][(c ^ rl) * 8]);
        a00 = __builtin_amdgcn_mfma_f32_16x16x32_f16(f0, f0, a00, 0, 0, 0);
        a10 = __builtin_amdgcn_mfma_f32_16x16x32_f16(f1, f0, a10, 0, 0, 0);
        a11 = __builtin_amdgcn_mfma_f32_16x16x32_f16(f1, f1, a11, 0, 0, 0);
    }

    #pragma unroll
    for (int r = 0; r < 4; ++r) {
        int i = ch * 4 + r, j = rl;
        if (i > j) xs_w[128 + (i * (i - 1)) / 2 + j] = (f16)a00[r];
    }
    #pragma unroll
    for (int r = 0; r < 4; ++r) {
        int i = 16 + ch * 4 + r, j = rl;
        if (i < 27) xs_w[128 + (i * (i - 1)) / 2 + j] = (f16)a10[r];
    }
    #pragma unroll
    for (int r = 0; r < 4; ++r) {
        int i = 16 + ch * 4 + r, j = 16 + rl;
        if (i < 27 && j < i) xs_w[128 + (i * (i - 1)) / 2 + j] = (f16)a11[r];
    }
    #pragma unroll
    for (int d = lane; d < 128; d += 64) xs_w[d] = F[wave][0][d];
    __syncthreads();

    {
        int b = b0 + wave;
        f16x8 v = *(const f16x8*)(&xs_w[lane * 8]);
        *(f16x8*)(x + (size_t)b * 512 + lane * 8) = v;
    }
}

// ---------------------------------------------------------------------------
extern "C" void kernel_launch(void* const* d_in, const int* in_sizes, int n_in,
                              void* d_out, int out_size, void* d_ws, size_t ws_size,
                              hipStream_t stream)
{
    (void)n_in; (void)out_size; (void)ws_size;
    const float* dense  = (const float*)d_in[0];
    const int*   sparse = (const int*)  d_in[1];
    const float* emb    = (const float*)d_in[2];
    const float* bw0 = (const float*)d_in[3];
    const float* bb0 = (const float*)d_in[4];
    const float* bw1 = (const float*)d_in[5];
    const float* bb1 = (const float*)d_in[6];
    const float* bw2 = (const float*)d_in[7];
    const float* bb2 = (const float*)d_in[8];
    const float* tw0 = (const float*)d_in[9];
    const float* tb0 = (const float*)d_in[10];
    const float* tw1 = (const float*)d_in[11];
    const float* tb1 = (const float*)d_in[12];
    const float* tw2 = (const float*)d_in[13];
    const float* tb2 = (const float*)d_in[14];
    const float* tw3 = (const float*)d_in[15];
    const float* tb3 = (const float*)d_in[16];
    const float* tw4 = (const float*)d_in[17];
    const float* tb4 = (const float*)d_in[18];
    float* out = (float*)d_out;

    const int B = in_sizes[0] / 13;
    const int V = in_sizes[2] / (26 * 128);

    char* ws = (char*)d_ws;
    size_t off = 0;
    auto alloc = [&](size_t bytes) {
        char* p = ws + off;
        off += (bytes + 255) & ~(size_t)255;
        return p;
    };
    f16* S1   = (f16*)alloc((size_t)B * 1024 * 2); // act0 (B,512) then t2 (B,1024)
    f16* t1   = (f16*)alloc((size_t)B * 1024 * 2); // (B,1024)
    f16* S3   = (f16*)alloc((size_t)B * 512 * 2);  // x (B,512) then t3 (B,512)
    f16* S4   = (f16*)alloc((size_t)B * 256 * 2);  // act1 (B,256)
    f16* act2 = (f16*)alloc((size_t)B * 128 * 2);  // bot_out (B,128)
    float* partial = (float*)alloc((size_t)B * 2 * 4);
    f16* bw1T = (f16*)alloc((size_t)256 * 512 * 2);
    f16* bw2T = (f16*)alloc((size_t)128 * 256 * 2);
    f16* tw0T = (f16*)alloc((size_t)1024 * 512 * 2);
    f16* tw1T = (f16*)alloc((size_t)1024 * 1024 * 2);
    f16* tw2T = (f16*)alloc((size_t)512 * 1024 * 2);
    f16* tw3T = (f16*)alloc((size_t)256 * 512 * 2);
    f16* act0 = S1; f16* t2 = S1;
    f16* x    = S3; f16* t3 = S3;
    f16* act1 = S4;

    ConvtArgs ca;
    ca.d[0] = { bw1, bw1T,  512,  256,  512,   0 };
    ca.d[1] = { bw2, bw2T,  256,  128,  256,  32 };
    ca.d[2] = { tw0, tw0T,  479, 1024,  512,  40 };
    ca.d[3] = { tw1, tw1T, 1024, 1024, 1024, 168 };
    ca.d[4] = { tw2, tw2T, 1024,  512, 1024, 424 };
    ca.d[5] = { tw3, tw3T,  512,  256,  512, 552 };
    convtbot_kernel<<<584 + B / 64, 256, 0, stream>>>(ca, dense, bw0, bb0, act0);

    gemm_f16<<<dim3( 256/128, B/128), 256, 0, stream>>>(act0, bw1T, bb1, act1,  256,  512, nullptr, nullptr);
    gemm_f16<<<dim3( 128/128, B/128), 256, 0, stream>>>(act1, bw2T, bb2, act2,  128,  256, nullptr, nullptr);
    interact_mfma<<<B / 4, 256, 0, stream>>>(act2, emb, sparse, x, V);
    gemm256_8ph<<<dim3(1024/256, B/256), 512, 0, stream>>>(x,  tw0T, tb0, t1, 1024,  512);
    gemm256_8ph<<<dim3(1024/256, B/256), 512, 0, stream>>>(t1, tw1T, tb1, t2, 1024, 1024);
    gemm256_8ph<<<dim3( 512/256, B/256), 512, 0, stream>>>(t2, tw2T, tb2, t3,  512, 1024);
    gemm_f16<<<dim3( 256/128, B/128), 256, 0, stream>>>(t3, tw3T, tb3, nullptr, 256, 512, tw4, partial);
    finish_kernel<<<B / 256, 256, 0, stream>>>(partial, tb4, out);
}

// Round 20
// 346.139 us; speedup vs baseline: 1.0910x; 1.0910x over previous
//
#include <hip/hip_runtime.h>

typedef _Float16 f16;
typedef __attribute__((ext_vector_type(2))) _Float16 f16x2;
typedef __attribute__((ext_vector_type(4))) _Float16 f16x4;
typedef __attribute__((ext_vector_type(8))) _Float16 f16x8;
typedef __attribute__((ext_vector_type(4))) float f32x4;

#define BM 128
#define BN 128
#define BK 32

__device__ __forceinline__ void gl_lds16(const void* g, void* l) {
    __builtin_amdgcn_global_load_lds(
        (const __attribute__((address_space(1))) void*)g,
        (__attribute__((address_space(3))) void*)l, 16, 0, 0);
}

// ---------------------------------------------------------------------------
// Fused: 6x transpose+convert (blocks 0..583) + bottom layer 0 (registers+LDS).
// ---------------------------------------------------------------------------
struct ConvtDesc { const float* src; f16* dst; int K, N, Kpad, tileOff; };
struct ConvtArgs { ConvtDesc d[6]; };

__global__ void convtbot_kernel(ConvtArgs args, const float* __restrict__ xin,
                                const float* __restrict__ bw0,
                                const float* __restrict__ bb0, f16* __restrict__ act0)
{
    int tid = threadIdx.x;
    if (blockIdx.x >= 584) {
        __shared__ float xs[64][13];
        int rbase = (blockIdx.x - 584) * 64;
        int n0 = tid * 2;
        float wr0[13], wr1[13];
        #pragma unroll
        for (int k = 0; k < 13; ++k) {
            wr0[k] = bw0[k * 512 + n0];
            wr1[k] = bw0[k * 512 + n0 + 1];
        }
        float b0v = bb0[n0], b1v = bb0[n0 + 1];
        for (int t = tid; t < 64 * 13; t += 256)
            xs[t / 13][t % 13] = xin[(size_t)rbase * 13 + t];
        __syncthreads();
        #pragma unroll 4
        for (int r = 0; r < 64; ++r) {
            float a0 = b0v, a1 = b1v;
            #pragma unroll
            for (int k = 0; k < 13; ++k) {
                float xv = xs[r][k];
                a0 += xv * wr0[k];
                a1 += xv * wr1[k];
            }
            f16x2 v;
            v[0] = (f16)fmaxf(a0, 0.f);
            v[1] = (f16)fmaxf(a1, 0.f);
            *(f16x2*)(act0 + (size_t)(rbase + r) * 512 + n0) = v;
        }
        return;
    }
    __shared__ float tile[64][65];
    int bid = blockIdx.x;
    int w = 0;
    #pragma unroll
    for (int i = 1; i < 6; ++i) if (bid >= args.d[i].tileOff) w = i;
    const float* __restrict__ src = args.d[w].src;
    f16* __restrict__ dst = args.d[w].dst;
    int K = args.d[w].K, N = args.d[w].N, Kpad = args.d[w].Kpad;
    int local = bid - args.d[w].tileOff;
    int tk = Kpad >> 6;
    int k0 = (local % tk) * 64;
    int n0 = (local / tk) * 64;
    #pragma unroll
    for (int it = 0; it < 16; ++it) {
        int idx = it * 256 + tid;
        int kr = idx >> 6, nc = idx & 63;
        float v = 0.f;
        if (k0 + kr < K) v = src[(size_t)(k0 + kr) * N + n0 + nc];
        tile[kr][nc] = v;
    }
    __syncthreads();
    #pragma unroll
    for (int it = 0; it < 16; ++it) {
        int idx = it * 256 + tid;
        int nr = idx >> 6, kc = idx & 63;
        dst[(size_t)(n0 + nr) * Kpad + k0 + kc] = (f16)tile[kc][nr];
    }
}

// ---------------------------------------------------------------------------
// 128x128 MFMA f16 GEMM, BK=32, double-buffered, counted-vmcnt, LDS-bounce
// epilogue. If w4 != nullptr: fused final-layer partial dot (t4 never
// materialized) -- r18-verified, -35 us vs separate top4 kernel.
// ---------------------------------------------------------------------------
__global__ void gemm_f16(const f16* __restrict__ A, const f16* __restrict__ WT,
                         const float* __restrict__ bias, f16* __restrict__ C,
                         int N, int K,
                         const float* __restrict__ w4, float* __restrict__ partial)
{
    __shared__ __align__(16) f16 sm[16384];
    f16* lsA0 = sm;
    f16* lsB0 = sm + 8192;
    int tid  = threadIdx.x;
    int lane = tid & 63;
    int wave = tid >> 6;
    int brow = blockIdx.y * BM;
    int bcol = blockIdx.x * BN;
    int wr = wave >> 1, wc = wave & 1;

    int rsel = lane & 15;
    int k8   = lane >> 4;

    auto stage = [&](int buf, int kt) {
        int k0 = kt * BK;
        #pragma unroll
        for (int i = 0; i < 2; ++i) {
            int flat = i * 256 + tid;
            int row  = flat >> 2;
            int slot = flat & 3;
            int sg   = slot ^ ((row >> 1) & 3);
            gl_lds16(A  + (size_t)(brow + row) * K + k0 + sg * 8, lsA0 + buf * 4096 + flat * 8);
            gl_lds16(WT + (size_t)(bcol + row) * K + k0 + sg * 8, lsB0 + buf * 4096 + flat * 8);
        }
    };

    int nK = K / BK;
    f32x4 acc[4][4] = {};
    stage(0, 0);
    for (int kt = 0; kt < nK; ++kt) {
        int cur = kt & 1;
        if (kt + 1 < nK) {
            stage(cur ^ 1, kt + 1);
            asm volatile("s_waitcnt vmcnt(4)" ::: "memory");
        } else {
            asm volatile("s_waitcnt vmcnt(0)" ::: "memory");
        }
        __builtin_amdgcn_s_barrier();

        __builtin_amdgcn_s_setprio(1);
        f16x8 aF[4], bF[4];
        #pragma unroll
        for (int m = 0; m < 4; ++m) {
            int ra = wr * 64 + m * 16 + rsel;
            int sa = k8 ^ ((ra >> 1) & 3);
            aF[m] = *(const f16x8*)(lsA0 + cur * 4096 + ra * 32 + sa * 8);
        }
        #pragma unroll
        for (int n = 0; n < 4; ++n) {
            int rb = wc * 64 + n * 16 + rsel;
            int sb = k8 ^ ((rb >> 1) & 3);
            bF[n] = *(const f16x8*)(lsB0 + cur * 4096 + rb * 32 + sb * 8);
        }
        #pragma unroll
        for (int m = 0; m < 4; ++m)
            #pragma unroll
            for (int n = 0; n < 4; ++n)
                acc[m][n] = __builtin_amdgcn_mfma_f32_16x16x32_f16(aF[m], bF[n], acc[m][n], 0, 0, 0);
        __builtin_amdgcn_s_setprio(0);
        asm volatile("s_waitcnt lgkmcnt(0)" ::: "memory");
        __builtin_amdgcn_s_barrier();
    }

    #pragma unroll
    for (int n = 0; n < 4; ++n) {
        int col = wc * 64 + n * 16 + rsel;
        float bv = bias[bcol + col];
        int ch = (col >> 3) ^ (k8 << 2);
        #pragma unroll
        for (int m = 0; m < 4; ++m) {
            int row = wr * 64 + m * 16 + k8 * 4;
            #pragma unroll
            for (int r = 0; r < 4; ++r)
                sm[(row + r) * 128 + ch * 8 + (col & 7)] = (f16)fmaxf(acc[m][n][r] + bv, 0.f);
        }
    }
    __syncthreads();
    if (w4 == nullptr) {
        int ch = tid & 15, r0 = tid >> 4;
        #pragma unroll
        for (int p = 0; p < 8; ++p) {
            int row = r0 + p * 16;
            int sch = ch ^ (((row >> 2) & 3) << 2);
            f16x8 v = *(const f16x8*)(sm + row * 128 + sch * 8);
            *(f16x8*)(C + (size_t)(brow + row) * N + bcol + ch * 8) = v;
        }
    } else {
        // fused top4: per-row 128-col partial dot of relu'd C-tile with w4
        int r = tid >> 1, h = tid & 1;
        int s4 = ((r >> 2) & 3) << 2;
        float a2 = 0.f;
        #pragma unroll
        for (int i = 0; i < 8; ++i) {
            int cc = h * 8 + i;                       // 16 chunks of 8 cols
            f16x8 cv = *(const f16x8*)(sm + r * 128 + (cc ^ s4) * 8);
            #pragma unroll
            for (int e = 0; e < 8; ++e)
                a2 += (float)cv[e] * w4[bcol + cc * 8 + e];
        }
        a2 += __shfl_xor(a2, 1, 64);
        if (h == 0) partial[(size_t)(brow + r) * 2 + blockIdx.x] = a2;
    }
}

// ---------------------------------------------------------------------------
// finish: out[b] = relu(partial[b][0] + partial[b][1] + bias)
// ---------------------------------------------------------------------------
__global__ void finish_kernel(const float* __restrict__ partial,
                              const float* __restrict__ b4, float* __restrict__ out)
{
    int b = blockIdx.x * 256 + threadIdx.x;
    out[b] = fmaxf(partial[(size_t)b * 2] + partial[(size_t)b * 2 + 1] + b4[0], 0.f);
}

// ---------------------------------------------------------------------------
// 256x256 MFMA f16 GEMM, BK=64, 8 waves, 4-phase dedup schedule (16x16x32),
// compiler-managed lgkm between ds_read and MFMA, counted vmcnt (r13/r16/r18-
// verified best configuration; 32x32x16 variant regressed in r19).
// ---------------------------------------------------------------------------
#define VM(n) asm volatile("s_waitcnt vmcnt(" #n ")" ::: "memory")
#define LGKM0 asm volatile("s_waitcnt lgkmcnt(0)" ::: "memory")

#define DSREAD_A(MH)                                                            \
    {                                                                           \
        const f16* pA = ls + cb * 32768 + (MH * 2) * 8192;                      \
        _Pragma("unroll")                                                       \
        for (int m = 0; m < 4; ++m) {                                           \
            int ra = wmq * 64 + m * 16 + rsel;                                  \
            _Pragma("unroll")                                                   \
            for (int ks = 0; ks < 2; ++ks) {                                    \
                int s = (ks * 4 + k8) ^ (ra & 7);                               \
                aF[m][ks] = *(const f16x8*)(pA + ra * 64 + s * 8);              \
            }                                                                   \
        }                                                                       \
    }

#define DSREAD_B(NH)                                                            \
    {                                                                           \
        const f16* pB = ls + cb * 32768 + (NH * 2 + 1) * 8192;                  \
        _Pragma("unroll")                                                       \
        for (int n = 0; n < 2; ++n) {                                           \
            int rb = wnq * 32 + n * 16 + rsel;                                  \
            _Pragma("unroll")                                                   \
            for (int ks = 0; ks < 2; ++ks) {                                    \
                int s = (ks * 4 + k8) ^ (rb & 7);                               \
                bF[NH][n][ks] = *(const f16x8*)(pB + rb * 64 + s * 8);          \
            }                                                                   \
        }                                                                       \
    }

#define MFMAQ(q, NH)                                                            \
    __builtin_amdgcn_s_barrier();                                               \
    __builtin_amdgcn_s_setprio(1);                                              \
    _Pragma("unroll")                                                           \
    for (int m = 0; m < 4; ++m)                                                 \
        _Pragma("unroll")                                                       \
        for (int n = 0; n < 2; ++n)                                             \
            _Pragma("unroll")                                                   \
            for (int ks = 0; ks < 2; ++ks)                                      \
                acc[q][m][n] = __builtin_amdgcn_mfma_f32_16x16x32_f16(          \
                    aF[m][ks], bF[NH][n][ks], acc[q][m][n], 0, 0, 0);           \
    __builtin_amdgcn_s_setprio(0);

__global__ __launch_bounds__(512, 2) void gemm256_8ph(
    const f16* __restrict__ A, const f16* __restrict__ WT,
    const float* __restrict__ bias, f16* __restrict__ C, int N, int K)
{
    __shared__ __align__(16) f16 ls[2 * 4 * 128 * 64];   // 128 KiB
    int tid  = threadIdx.x;
    int lane = tid & 63;
    int wid  = tid >> 6;
    int wmq = wid >> 2, wnq = wid & 3;

    int nbx = gridDim.x;
    int flat = blockIdx.y * nbx + blockIdx.x;
    int nchunk = (nbx * gridDim.y) >> 3;
    int nf = (flat & 7) * nchunk + (flat >> 3);
    int bx = nf % nbx, by = nf / nbx;
    int brow = by * 256, bcol = bx * 256;

    int rsel = lane & 15;
    int k8   = lane >> 4;
    const size_t szK = (size_t)K;

    auto stage_half = [&](int dbuf, int hreg, int kt) {
        const f16* mat = (hreg & 1) ? WT : A;
        int base = (hreg & 1) ? bcol : brow;
        const f16* g = mat + (size_t)(base + (hreg >> 1) * 128) * szK + kt * 64;
        f16* d = ls + dbuf * 32768 + hreg * 8192;
        #pragma unroll
        for (int i = 0; i < 2; ++i) {
            int fl  = i * 512 + tid;
            int row = fl >> 3, sl = fl & 7;
            int sg  = sl ^ (row & 7);
            gl_lds16(g + (size_t)row * szK + sg * 8, d + fl * 8);
        }
    };

    int nK = K / 64;
    f32x4 acc[4][4][2] = {};

    stage_half(0, 0, 0); stage_half(0, 1, 0);
    stage_half(0, 3, 0); stage_half(0, 2, 0);
    VM(2);
    __builtin_amdgcn_s_barrier();

    for (int kt = 0; kt < nK; ++kt) {
        int cb = kt & 1, nb = cb ^ 1;
        bool nl = (kt + 1 < nK);
        f16x8 aF[4][2], bF[2][2][2];
        DSREAD_A(0)
        DSREAD_B(0)
        DSREAD_B(1)
        if (nl) stage_half(nb, 0, kt + 1);
        MFMAQ(0, 0)
        __builtin_amdgcn_s_barrier();
        if (nl) { stage_half(nb, 1, kt + 1); VM(4); } else { VM(0); }
        MFMAQ(1, 1)
        __builtin_amdgcn_s_barrier();
        DSREAD_A(1)
        if (nl) stage_half(nb, 3, kt + 1);
        MFMAQ(2, 1)
        __builtin_amdgcn_s_barrier();
        if (nl) { stage_half(nb, 2, kt + 1); VM(2); }
        MFMAQ(3, 0)
        LGKM0;
        __builtin_amdgcn_s_barrier();
    }

    const int mhq[4] = {0, 0, 1, 1};
    const int nhq[4] = {0, 1, 1, 0};
    #pragma unroll
    for (int q = 0; q < 4; ++q) {
        #pragma unroll
        for (int n = 0; n < 2; ++n) {
            int col = nhq[q] * 128 + wnq * 32 + n * 16 + rsel;
            float bv = bias[bcol + col];
            int ch = (col >> 3) ^ (k8 << 2);
            #pragma unroll
            for (int m = 0; m < 4; ++m) {
                int row = mhq[q] * 128 + wmq * 64 + m * 16 + k8 * 4;
                #pragma unroll
                for (int r = 0; r < 4; ++r)
                    ls[(row + r) * 256 + ch * 8 + (col & 7)] = (f16)fmaxf(acc[q][m][n][r] + bv, 0.f);
            }
        }
    }
    __syncthreads();
    {
        int ch = tid & 31, r0 = tid >> 5;
        #pragma unroll
        for (int p = 0; p < 16; ++p) {
            int row = r0 + p * 16;
            int sch = ch ^ (((row >> 2) & 3) << 2);
            f16x8 v = *(const f16x8*)(ls + row * 256 + sch * 8);
            *(f16x8*)(C + (size_t)(brow + row) * N + bcol + ch * 8) = v;
        }
    }
}

// ---------------------------------------------------------------------------
// MFMA interaction: 4 samples/block, one wave per sample. 32 KiB LDS
// (xs overlaid on F rows 27..30) -> 5 blocks/CU.
// ---------------------------------------------------------------------------
__global__ void interact_mfma(const f16* __restrict__ botout,
                              const float* __restrict__ emb,
                              const int* __restrict__ sparse,
                              f16* __restrict__ x, int V)
{
    __shared__ __align__(16) f16 F[4][32][128];
    int tid  = threadIdx.x;
    int lane = tid & 63, wave = tid >> 6;
    int b0 = blockIdx.x * 4;
    f16* xs_w = &F[wave][27][0];

    for (int t = tid; t < 4 * 27 * 16; t += 256) {
        int s   = t / (27 * 16);
        int rem = t - s * (27 * 16);
        int r   = rem >> 4;
        int c   = rem & 15;
        int b   = b0 + s;
        f16x8 v;
        if (r == 0) {
            v = *(const f16x8*)(botout + (size_t)b * 128 + c * 8);
        } else {
            const f32x4* src = (const f32x4*)(emb + ((size_t)(r - 1) * V + sparse[b * 26 + (r - 1)]) * 128 + c * 8);
            f32x4 u0 = src[0], u1 = src[1];
            #pragma unroll
            for (int e = 0; e < 4; ++e) { v[e] = (f16)u0[e]; v[4 + e] = (f16)u1[e]; }
        }
        *(f16x8*)(&F[s][r][(c ^ (r & 15)) * 8]) = v;
    }
    if (tid < 4 * 33) {
        int s = tid / 33;
        (&F[s][27][0])[479 + tid % 33] = (f16)0;
    }
    __syncthreads();

    f32x4 a00 = {}, a10 = {}, a11 = {};
    int rl = lane & 15, ch = lane >> 4;
    #pragma unroll
    for (int ks = 0; ks < 4; ++ks) {
        int c = ks * 4 + ch;
        f16x8 f0 = *(const f16x8*)(&F[wave][rl]     [(c ^ rl) * 8]);
        f16x8 f1 = *(const f16x8*)(&F[wave][16 + rl][(c ^ rl) * 8]);
        a00 = __builtin_amdgcn_mfma_f32_16x16x32_f16(f0, f0, a00, 0, 0, 0);
        a10 = __builtin_amdgcn_mfma_f32_16x16x32_f16(f1, f0, a10, 0, 0, 0);
        a11 = __builtin_amdgcn_mfma_f32_16x16x32_f16(f1, f1, a11, 0, 0, 0);
    }

    #pragma unroll
    for (int r = 0; r < 4; ++r) {
        int i = ch * 4 + r, j = rl;
        if (i > j) xs_w[128 + (i * (i - 1)) / 2 + j] = (f16)a00[r];
    }
    #pragma unroll
    for (int r = 0; r < 4; ++r) {
        int i = 16 + ch * 4 + r, j = rl;
        if (i < 27) xs_w[128 + (i * (i - 1)) / 2 + j] = (f16)a10[r];
    }
    #pragma unroll
    for (int r = 0; r < 4; ++r) {
        int i = 16 + ch * 4 + r, j = 16 + rl;
        if (i < 27 && j < i) xs_w[128 + (i * (i - 1)) / 2 + j] = (f16)a11[r];
    }
    #pragma unroll
    for (int d = lane; d < 128; d += 64) xs_w[d] = F[wave][0][d];
    __syncthreads();

    {
        int b = b0 + wave;
        f16x8 v = *(const f16x8*)(&xs_w[lane * 8]);
        *(f16x8*)(x + (size_t)b * 512 + lane * 8) = v;
    }
}

// ---------------------------------------------------------------------------
extern "C" void kernel_launch(void* const* d_in, const int* in_sizes, int n_in,
                              void* d_out, int out_size, void* d_ws, size_t ws_size,
                              hipStream_t stream)
{
    (void)n_in; (void)out_size; (void)ws_size;
    const float* dense  = (const float*)d_in[0];
    const int*   sparse = (const int*)  d_in[1];
    const float* emb    = (const float*)d_in[2];
    const float* bw0 = (const float*)d_in[3];
    const float* bb0 = (const float*)d_in[4];
    const float* bw1 = (const float*)d_in[5];
    const float* bb1 = (const float*)d_in[6];
    const float* bw2 = (const float*)d_in[7];
    const float* bb2 = (const float*)d_in[8];
    const float* tw0 = (const float*)d_in[9];
    const float* tb0 = (const float*)d_in[10];
    const float* tw1 = (const float*)d_in[11];
    const float* tb1 = (const float*)d_in[12];
    const float* tw2 = (const float*)d_in[13];
    const float* tb2 = (const float*)d_in[14];
    const float* tw3 = (const float*)d_in[15];
    const float* tb3 = (const float*)d_in[16];
    const float* tw4 = (const float*)d_in[17];
    const float* tb4 = (const float*)d_in[18];
    float* out = (float*)d_out;

    const int B = in_sizes[0] / 13;
    const int V = in_sizes[2] / (26 * 128);

    char* ws = (char*)d_ws;
    size_t off = 0;
    auto alloc = [&](size_t bytes) {
        char* p = ws + off;
        off += (bytes + 255) & ~(size_t)255;
        return p;
    };
    f16* S1   = (f16*)alloc((size_t)B * 1024 * 2); // act0 (B,512) then t2 (B,1024)
    f16* t1   = (f16*)alloc((size_t)B * 1024 * 2); // (B,1024)
    f16* S3   = (f16*)alloc((size_t)B * 512 * 2);  // x (B,512) then t3 (B,512)
    f16* S4   = (f16*)alloc((size_t)B * 256 * 2);  // act1 (B,256)
    f16* act2 = (f16*)alloc((size_t)B * 128 * 2);  // bot_out (B,128)
    float* partial = (float*)alloc((size_t)B * 2 * 4);
    f16* bw1T = (f16*)alloc((size_t)256 * 512 * 2);
    f16* bw2T = (f16*)alloc((size_t)128 * 256 * 2);
    f16* tw0T = (f16*)alloc((size_t)1024 * 512 * 2);
    f16* tw1T = (f16*)alloc((size_t)1024 * 1024 * 2);
    f16* tw2T = (f16*)alloc((size_t)512 * 1024 * 2);
    f16* tw3T = (f16*)alloc((size_t)256 * 512 * 2);
    f16* act0 = S1; f16* t2 = S1;
    f16* x    = S3; f16* t3 = S3;
    f16* act1 = S4;

    ConvtArgs ca;
    ca.d[0] = { bw1, bw1T,  512,  256,  512,   0 };
    ca.d[1] = { bw2, bw2T,  256,  128,  256,  32 };
    ca.d[2] = { tw0, tw0T,  479, 1024,  512,  40 };
    ca.d[3] = { tw1, tw1T, 1024, 1024, 1024, 168 };
    ca.d[4] = { tw2, tw2T, 1024,  512, 1024, 424 };
    ca.d[5] = { tw3, tw3T,  512,  256,  512, 552 };
    convtbot_kernel<<<584 + B / 64, 256, 0, stream>>>(ca, dense, bw0, bb0, act0);

    gemm_f16<<<dim3( 256/128, B/128), 256, 0, stream>>>(act0, bw1T, bb1, act1,  256,  512, nullptr, nullptr);
    gemm_f16<<<dim3( 128/128, B/128), 256, 0, stream>>>(act1, bw2T, bb2, act2,  128,  256, nullptr, nullptr);
    interact_mfma<<<B / 4, 256, 0, stream>>>(act2, emb, sparse, x, V);
    gemm256_8ph<<<dim3(1024/256, B/256), 512, 0, stream>>>(x,  tw0T, tb0, t1, 1024,  512);
    gemm256_8ph<<<dim3(1024/256, B/256), 512, 0, stream>>>(t1, tw1T, tb1, t2, 1024, 1024);
    gemm256_8ph<<<dim3( 512/256, B/256), 512, 0, stream>>>(t2, tw2T, tb2, t3,  512, 1024);
    gemm_f16<<<dim3( 256/128, B/128), 256, 0, stream>>>(t3, tw3T, tb3, nullptr, 256, 512, tw4, partial);
    finish_kernel<<<B / 256, 256, 0, stream>>>(partial, tb4, out);
}